// Round 4
// baseline (654.804 us; speedup 1.0000x reference)
//
#include <hip/hip_runtime.h>

// Swin shifted-window MHSA, fused per-window kernel, v3b.
// 1 block = 2 windows (pipelined), 256 threads = 4 waves, wave h = head h.
// Register-resident attention (swapped Q/K proj + consistent MFMA k-mapping),
// v_cvt_pk_bf16_f32 packing, exp2-domain softmax, prefetched second window.

typedef __attribute__((ext_vector_type(8))) short bf16x8;   // 8 bf16 = 4 VGPR
typedef __attribute__((ext_vector_type(4))) float f32x4;    // MFMA C/D

#define MFMA16(a, b, c) __builtin_amdgcn_mfma_f32_16x16x32_bf16((a), (b), (c), 0, 0, 0)
#define EXP2F(x) __builtin_amdgcn_exp2f(x)

#define XW_OFF 0         // 16KB: Xw [64][128] bf16, swizzled
#define STG_OFF 16384    // 16KB: attn-out staging [64][128] bf16, swizzled
#define LDS_BYTES 32768

__device__ __forceinline__ unsigned int cvt_pk(float lo, float hi) {
  unsigned int r;
  asm("v_cvt_pk_bf16_f32 %0, %1, %2" : "=v"(r) : "v"(lo), "v"(hi));
  return r;
}
__device__ __forceinline__ unsigned short f2bf1(float f) {
  return (unsigned short)(cvt_pk(f, f) & 0xffffu);
}
__device__ __forceinline__ bf16x8 pack8(f32x4 a, f32x4 b) {
  union { unsigned int w[4]; bf16x8 v; } u;
  u.w[0] = cvt_pk(a[0], a[1]); u.w[1] = cvt_pk(a[2], a[3]);
  u.w[2] = cvt_pk(b[0], b[1]); u.w[3] = cvt_pk(b[2], b[3]);
  return u.v;
}
__device__ __forceinline__ bf16x8 packf4(float4 lo, float4 hi) {
  union { unsigned int w[4]; bf16x8 v; } u;
  u.w[0] = cvt_pk(lo.x, lo.y); u.w[1] = cvt_pk(lo.z, lo.w);
  u.w[2] = cvt_pk(hi.x, hi.y); u.w[3] = cvt_pk(hi.z, hi.w);
  return u.v;
}

// prep: transpose weights to bf16 Wt[n][k] + expand rel-pos bias to [4][64][64] f32
// pre-scaled by log2(e) (softmax runs in exp2 domain).
__global__ void prep_kernel(const float* __restrict__ wq, const float* __restrict__ wk,
                            const float* __restrict__ wv, const float* __restrict__ wo,
                            const float* __restrict__ bias_table,
                            unsigned short* __restrict__ wt, float* __restrict__ bias_full) {
  int tid = blockIdx.x * 256 + threadIdx.x;            // 65536 threads
  int m = tid >> 14, idx = tid & 16383;
  int n = idx >> 7, k = idx & 127;
  const float* w = (m == 0) ? wq : (m == 1) ? wk : (m == 2) ? wv : wo;
  wt[m * 16384 + n * 128 + k] = f2bf1(w[k * 128 + n]);
  if (tid < 16384) {                                    // bias_full[h][s1][s2]
    int h = tid >> 12, r = tid & 4095;
    int s1 = r >> 6, s2 = r & 63;
    int rel = ((s1 >> 3) - (s2 >> 3) + 7) * 15 + ((s1 & 7) - (s2 & 7) + 7);
    bias_full[tid] = bias_table[rel * 4 + h] * 1.4426950408889634f;
  }
}

__device__ __forceinline__ const float* gsrc(const float* __restrict__ x, int bb, int wh,
                                             int ww, int ss, int cid) {
  int s = cid >> 4, cc = (cid & 15) << 3;
  int r0 = (wh * 8 + (s >> 3) + ss) & 127;   // roll(-ss): src = pos + ss (mod 128)
  int c0 = (ww * 8 + (s & 7) + ss) & 127;
  return x + ((bb * 16384 + r0 * 128 + c0) * 128 + cc);
}
__device__ __forceinline__ void store_xw(char* smem, int cid, bf16x8 v) {
  int s = cid >> 4, cc = (cid & 15) << 3;
  *(bf16x8*)(smem + XW_OFF + s * 256 + ((cc * 2) ^ ((s & 7) << 4))) = v;
}

__global__ __launch_bounds__(256, 4) void winattn_kernel(
    const float* __restrict__ x,
    const float* __restrict__ bq, const float* __restrict__ bk,
    const float* __restrict__ bv, const float* __restrict__ bo,
    const unsigned short* __restrict__ wt,
    const float* __restrict__ bias_full,
    const int* __restrict__ shiftp,
    float* __restrict__ out) {
  __shared__ __align__(16) char smem[LDS_BYTES];
  const int tid = threadIdx.x;
  const int h = tid >> 6, lane = tid & 63;
  const int g = lane >> 4, c16 = lane & 15;
  const int shift = shiftp[0];
  const int ss = shift ? 4 : 0;
  const f32x4 z4 = {0.f, 0.f, 0.f, 0.f};

  const int win0 = blockIdx.x, win1 = blockIdx.x + 2048;
  const int bb1 = win1 >> 8, wh1 = (win1 >> 4) & 15, ww1 = win1 & 15;

  // ---- Prologue: gather window 0 -> LDS; issue first half of window 1 gather ----
  {
    const int bb0 = win0 >> 8, wh0 = (win0 >> 4) & 15, ww0 = win0 & 15;
#pragma unroll
    for (int it = 0; it < 4; ++it) {
      int cid = tid + it * 256;
      const float* src = gsrc(x, bb0, wh0, ww0, ss, cid);
      float4 lo = *(const float4*)src;
      float4 hi = *(const float4*)(src + 4);
      store_xw(smem, cid, packf4(lo, hi));
    }
  }
  float4 pre0[4], pre1[4];
  {
    const float* s0 = gsrc(x, bb1, wh1, ww1, ss, tid);
    const float* s1 = gsrc(x, bb1, wh1, ww1, ss, tid + 256);
    pre0[0] = *(const float4*)s0; pre0[1] = *(const float4*)(s0 + 4);
    pre0[2] = *(const float4*)s1; pre0[3] = *(const float4*)(s1 + 4);
  }

  for (int w = 0; w < 2; ++w) {
    const int win = w ? win1 : win0;
    const int wh = (win >> 4) & 15, ww = win & 15;
    __syncthreads();   // Xw ready; STG free

    // ---- Phase B: fused Q^T / K^T / V projections for this head ----
    f32x4 qacc[2][4], kacc[2][4], vacc[4][2];
#pragma unroll
    for (int i = 0; i < 4; ++i) {
      qacc[0][i] = z4; qacc[1][i] = z4;
      kacc[0][i] = z4; kacc[1][i] = z4;
      vacc[i][0] = z4; vacc[i][1] = z4;
    }
    const unsigned short* wq_ = wt + (h * 32 + c16) * 128;
    const unsigned short* wk_ = wt + 16384 + (h * 32 + c16) * 128;
    const unsigned short* wv_ = wt + 32768 + (h * 32 + c16) * 128;
#pragma unroll
    for (int kk = 0; kk < 4; ++kk) {
      const int co = kk * 32 + g * 8;
      bf16x8 xfr[4];
#pragma unroll
      for (int t = 0; t < 4; ++t) {
        int row = t * 16 + c16;
        xfr[t] = *(const bf16x8*)(smem + XW_OFF + row * 256 + ((co * 2) ^ ((row & 7) << 4)));
      }
      bf16x8 wqf0 = *(const bf16x8*)(wq_ + co);
      bf16x8 wqf1 = *(const bf16x8*)(wq_ + 2048 + co);
      bf16x8 wkf0 = *(const bf16x8*)(wk_ + co);
      bf16x8 wkf1 = *(const bf16x8*)(wk_ + 2048 + co);
      bf16x8 wvf0 = *(const bf16x8*)(wv_ + co);
      bf16x8 wvf1 = *(const bf16x8*)(wv_ + 2048 + co);
#pragma unroll
      for (int t = 0; t < 4; ++t) {
        qacc[0][t] = MFMA16(wqf0, xfr[t], qacc[0][t]);
        qacc[1][t] = MFMA16(wqf1, xfr[t], qacc[1][t]);
        kacc[0][t] = MFMA16(wkf0, xfr[t], kacc[0][t]);
        kacc[1][t] = MFMA16(wkf1, xfr[t], kacc[1][t]);
        vacc[t][0] = MFMA16(xfr[t], wvf0, vacc[t][0]);
        vacc[t][1] = MFMA16(xfr[t], wvf1, vacc[t][1]);
      }
    }

    // bias (+ exp2-domain scale folded into Q), pack with k-mapping pi(g,j)=(j>>2)*16+g*4+(j&3)
    bf16x8 qb16[4], kb16[4], vb16[2][2];
    {
      const float scale = 0.17677669529663687f * 1.4426950408889634f;  // 1/sqrt(32)*log2e
      f32x4 bq4[2], bk4[2];
      bq4[0] = *(const f32x4*)(bq + h * 32 + g * 4);
      bq4[1] = *(const f32x4*)(bq + h * 32 + 16 + g * 4);
      bk4[0] = *(const f32x4*)(bk + h * 32 + g * 4);
      bk4[1] = *(const f32x4*)(bk + h * 32 + 16 + g * 4);
#pragma unroll
      for (int t = 0; t < 4; ++t) {
        f32x4 q0, q1, k0, k1;
#pragma unroll
        for (int r = 0; r < 4; ++r) {
          q0[r] = (qacc[0][t][r] + bq4[0][r]) * scale;
          q1[r] = (qacc[1][t][r] + bq4[1][r]) * scale;
          k0[r] = kacc[0][t][r] + bk4[0][r];
          k1[r] = kacc[1][t][r] + bk4[1][r];
        }
        qb16[t] = pack8(q0, q1);
        kb16[t] = pack8(k0, k1);
      }
      float bv0 = bv[h * 32 + c16];
      float bv1 = bv[h * 32 + 16 + c16];
#pragma unroll
      for (int ks = 0; ks < 2; ++ks) {
        f32x4 v00, v10, v01, v11;
#pragma unroll
        for (int r = 0; r < 4; ++r) {
          v00[r] = vacc[2 * ks][0][r] + bv0;
          v10[r] = vacc[2 * ks + 1][0][r] + bv0;
          v01[r] = vacc[2 * ks][1][r] + bv1;
          v11[r] = vacc[2 * ks + 1][1][r] + bv1;
        }
        vb16[ks][0] = pack8(v00, v10);
        vb16[ks][1] = pack8(v01, v11);
      }
    }

    // ---- Phase C: QK^T from registers. sc[a][b]: S^T[s2=a*16+g*4+r][s1=b*16+c16] ----
    f32x4 sc[4][4];
#pragma unroll
    for (int a = 0; a < 4; ++a)
#pragma unroll
      for (int b = 0; b < 4; ++b) sc[a][b] = MFMA16(kb16[a], qb16[b], z4);

    int w1i[4] = {0, 0, 0, 0};
    int w2i[4][4] = {};
    if (shift) {
#pragma unroll
      for (int b = 0; b < 4; ++b) {
        int s1 = b * 16 + c16;
        int r0 = (wh * 8 + (s1 >> 3) + ss) & 127;
        int c0 = (ww * 8 + (s1 & 7) + ss) & 127;
        w1i[b] = (r0 >> 3) * 16 + (c0 >> 3);
      }
#pragma unroll
      for (int a = 0; a < 4; ++a)
#pragma unroll
        for (int r = 0; r < 4; ++r) {
          int s2 = a * 16 + g * 4 + r;
          int r0 = (wh * 8 + (s2 >> 3) + ss) & 127;
          int c0 = (ww * 8 + (s2 & 7) + ss) & 127;
          w2i[a][r] = (r0 >> 3) * 16 + (c0 >> 3);
        }
    }

    // ---- softmax over s2 (exp2 domain), tree reductions ----
    bf16x8 pa[4][2];
    const float* bfh = bias_full + h * 4096 + c16 * 64 + g * 4;
#pragma unroll
    for (int b = 0; b < 4; ++b) {
      const float* bfr = bfh + b * 1024;
      f32x4 bia[4];
#pragma unroll
      for (int a = 0; a < 4; ++a) bia[a] = *(const f32x4*)(bfr + a * 16);
#pragma unroll
      for (int a = 0; a < 4; ++a)
#pragma unroll
        for (int r = 0; r < 4; ++r) {
          float v = sc[a][b][r] + bia[a][r];
          if (shift && (w1i[b] != w2i[a][r])) v -= 144.2695040888963f;  // -100*log2e
          sc[a][b][r] = v;
        }
      f32x4 m01, m23;
#pragma unroll
      for (int r = 0; r < 4; ++r) {
        m01[r] = fmaxf(sc[0][b][r], sc[1][b][r]);
        m23[r] = fmaxf(sc[2][b][r], sc[3][b][r]);
      }
      float mx = fmaxf(fmaxf(fmaxf(m01[0], m01[1]), fmaxf(m01[2], m01[3])),
                       fmaxf(fmaxf(m23[0], m23[1]), fmaxf(m23[2], m23[3])));
      mx = fmaxf(mx, __shfl_xor(mx, 16));
      mx = fmaxf(mx, __shfl_xor(mx, 32));
#pragma unroll
      for (int a = 0; a < 4; ++a)
#pragma unroll
        for (int r = 0; r < 4; ++r) sc[a][b][r] = EXP2F(sc[a][b][r] - mx);
      f32x4 s01, s23;
#pragma unroll
      for (int r = 0; r < 4; ++r) {
        s01[r] = sc[0][b][r] + sc[1][b][r];
        s23[r] = sc[2][b][r] + sc[3][b][r];
      }
      float sum = ((s01[0] + s01[1]) + (s01[2] + s01[3])) +
                  ((s23[0] + s23[1]) + (s23[2] + s23[3]));
      sum += __shfl_xor(sum, 16);
      sum += __shfl_xor(sum, 32);
      float inv = 1.0f / sum;
#pragma unroll
      for (int a = 0; a < 4; ++a)
#pragma unroll
        for (int r = 0; r < 4; ++r) sc[a][b][r] *= inv;
      pa[b][0] = pack8(sc[0][b], sc[1][b]);
      pa[b][1] = pack8(sc[2][b], sc[3][b]);
    }

    // issue second half of window-1 gather (covered by PV + staging + out-proj)
    if (w == 0) {
      const float* s2p = gsrc(x, bb1, wh1, ww1, ss, tid + 512);
      const float* s3p = gsrc(x, bb1, wh1, ww1, ss, tid + 768);
      pre1[0] = *(const float4*)s2p; pre1[1] = *(const float4*)(s2p + 4);
      pre1[2] = *(const float4*)s3p; pre1[3] = *(const float4*)(s3p + 4);
    }

    // ---- Phase D: PV from registers. o[b][nt]: O[s1=b*16+g*4+r][d=h*32+nt*16+c16] ----
    f32x4 o[4][2];
#pragma unroll
    for (int b = 0; b < 4; ++b) { o[b][0] = z4; o[b][1] = z4; }
#pragma unroll
    for (int b = 0; b < 4; ++b)
#pragma unroll
      for (int ks = 0; ks < 2; ++ks) {
        o[b][0] = MFMA16(pa[b][ks], vb16[ks][0], o[b][0]);
        o[b][1] = MFMA16(pa[b][ks], vb16[ks][1], o[b][1]);
      }

    __syncthreads();   // Xw reads done; safe to overwrite Xw (w==0) and write STG

    // ---- Phase E: store next window's Xw; stage attn-out (bf16, swizzled) ----
    if (w == 0) {
      store_xw(smem, tid,       packf4(pre0[0], pre0[1]));
      store_xw(smem, tid + 256, packf4(pre0[2], pre0[3]));
      store_xw(smem, tid + 512, packf4(pre1[0], pre1[1]));
      store_xw(smem, tid + 768, packf4(pre1[2], pre1[3]));
    }
#pragma unroll
    for (int b = 0; b < 4; ++b)
#pragma unroll
      for (int nt = 0; nt < 2; ++nt)
#pragma unroll
        for (int r = 0; r < 4; ++r) {
          int row = b * 16 + g * 4 + r;
          int col = h * 32 + nt * 16 + c16;
          *(unsigned short*)(smem + STG_OFF + row * 256 + ((col * 2) ^ ((row & 7) << 4))) =
              f2bf1(o[b][nt][r]);
        }
    __syncthreads();   // STG ready

    // ---- Phase F: output projection -> global fp32 ----
    {
      f32x4 acc[8];
#pragma unroll
      for (int nt = 0; nt < 8; ++nt) acc[nt] = z4;
      const int arow = h * 16 + c16;
      const int asw = (arow & 7) << 4;
#pragma unroll
      for (int kk = 0; kk < 4; ++kk) {
        const int co = kk * 32 + g * 8;
        bf16x8 a = *(const bf16x8*)(smem + STG_OFF + arow * 256 + ((co * 2) ^ asw));
#pragma unroll
        for (int nt = 0; nt < 8; ++nt) {
          bf16x8 bfr = *(const bf16x8*)(wt + 49152 + (nt * 16 + c16) * 128 + co);
          acc[nt] = MFMA16(a, bfr, acc[nt]);
        }
      }
#pragma unroll
      for (int nt = 0; nt < 8; ++nt) {
        int n = nt * 16 + c16;
        float bn = bo[n];
#pragma unroll
        for (int r = 0; r < 4; ++r) {
          int row = h * 16 + g * 4 + r;
          out[(size_t)win * 8192 + (size_t)(row * 128 + n)] = acc[nt][r] + bn;
        }
      }
    }
  }
}

extern "C" void kernel_launch(void* const* d_in, const int* in_sizes, int n_in,
                              void* d_out, int out_size, void* d_ws, size_t ws_size,
                              hipStream_t stream) {
  const float* x = (const float*)d_in[0];
  const float* wq = (const float*)d_in[1];
  const float* bq = (const float*)d_in[2];
  const float* wk = (const float*)d_in[3];
  const float* bk = (const float*)d_in[4];
  const float* wv = (const float*)d_in[5];
  const float* bv = (const float*)d_in[6];
  const float* wo = (const float*)d_in[7];
  const float* bo = (const float*)d_in[8];
  const float* bias_table = (const float*)d_in[9];
  const int* shiftp = (const int*)d_in[10];

  unsigned short* wt = (unsigned short*)d_ws;                    // 4*128*128 bf16 = 128KB
  float* bias_full = (float*)((char*)d_ws + 131072);             // 4*64*64 f32 = 64KB

  prep_kernel<<<256, 256, 0, stream>>>(wq, wk, wv, wo, bias_table, wt, bias_full);
  winattn_kernel<<<2048, 256, 0, stream>>>(x, bq, bk, bv, bo, wt, bias_full, shiftp,
                                           (float*)d_out);
}

// Round 5
// 289.897 us; speedup vs baseline: 2.2587x; 2.2587x over previous
//
#include <hip/hip_runtime.h>

// Swin shifted-window MHSA, fused per-window kernel, v4.
// 1 block = 1 window (S=64 tokens, C=128), 512 threads = 8 waves.
// Wave (h, half): head h = wv>>1, half = wv&1 owns s1-tiles {2*half, 2*half+1}.
// Register-resident attention (swapped Q/K proj + consistent MFMA k-mapping),
// v_cvt_pk_bf16_f32 packing, exp2-domain softmax. K/V proj duplicated across
// the two waves of a head (MFMA is idle anyway); Q/QK/softmax/PV/out-proj halved.

typedef __attribute__((ext_vector_type(8))) short bf16x8;   // 8 bf16 = 4 VGPR
typedef __attribute__((ext_vector_type(4))) float f32x4;    // MFMA C/D

#define MFMA16(a, b, c) __builtin_amdgcn_mfma_f32_16x16x32_bf16((a), (b), (c), 0, 0, 0)
#define EXP2F(x) __builtin_amdgcn_exp2f(x)

#define LDS_BYTES 16384   // Xw [64][128] bf16 swizzled; reused as attn-out staging

__device__ __forceinline__ unsigned int cvt_pk(float lo, float hi) {
  unsigned int r;
  asm("v_cvt_pk_bf16_f32 %0, %1, %2" : "=v"(r) : "v"(lo), "v"(hi));
  return r;
}
__device__ __forceinline__ unsigned short f2bf1(float f) {
  return (unsigned short)(cvt_pk(f, f) & 0xffffu);
}
__device__ __forceinline__ bf16x8 pack8(f32x4 a, f32x4 b) {
  union { unsigned int w[4]; bf16x8 v; } u;
  u.w[0] = cvt_pk(a[0], a[1]); u.w[1] = cvt_pk(a[2], a[3]);
  u.w[2] = cvt_pk(b[0], b[1]); u.w[3] = cvt_pk(b[2], b[3]);
  return u.v;
}
__device__ __forceinline__ bf16x8 packf4(float4 lo, float4 hi) {
  union { unsigned int w[4]; bf16x8 v; } u;
  u.w[0] = cvt_pk(lo.x, lo.y); u.w[1] = cvt_pk(lo.z, lo.w);
  u.w[2] = cvt_pk(hi.x, hi.y); u.w[3] = cvt_pk(hi.z, hi.w);
  return u.v;
}

// prep: transpose weights to bf16 Wt[n][k] + expand rel-pos bias to [4][64][64] f32
// pre-scaled by log2(e) (softmax runs in exp2 domain).
__global__ void prep_kernel(const float* __restrict__ wq, const float* __restrict__ wk,
                            const float* __restrict__ wv, const float* __restrict__ wo,
                            const float* __restrict__ bias_table,
                            unsigned short* __restrict__ wt, float* __restrict__ bias_full) {
  int tid = blockIdx.x * 256 + threadIdx.x;            // 65536 threads
  int m = tid >> 14, idx = tid & 16383;
  int n = idx >> 7, k = idx & 127;
  const float* w = (m == 0) ? wq : (m == 1) ? wk : (m == 2) ? wv : wo;
  wt[m * 16384 + n * 128 + k] = f2bf1(w[k * 128 + n]);
  if (tid < 16384) {                                    // bias_full[h][s1][s2]
    int h = tid >> 12, r = tid & 4095;
    int s1 = r >> 6, s2 = r & 63;
    int rel = ((s1 >> 3) - (s2 >> 3) + 7) * 15 + ((s1 & 7) - (s2 & 7) + 7);
    bias_full[tid] = bias_table[rel * 4 + h] * 1.4426950408889634f;
  }
}

__global__ __launch_bounds__(512) void winattn_kernel(
    const float* __restrict__ x,
    const float* __restrict__ bq, const float* __restrict__ bk,
    const float* __restrict__ bv, const float* __restrict__ bo,
    const unsigned short* __restrict__ wt,
    const float* __restrict__ bias_full,
    const int* __restrict__ shiftp,
    float* __restrict__ out) {
  __shared__ __align__(16) char smem[LDS_BYTES];
  const int tid = threadIdx.x;
  const int wv = tid >> 6, lane = tid & 63;
  const int h = wv >> 1, half = wv & 1;       // head, s1-half
  const int g = lane >> 4, c16 = lane & 15;
  const int win = blockIdx.x;
  const int bb = win >> 8, wh = (win >> 4) & 15, ww = win & 15;
  const int shift = shiftp[0];
  const int ss = shift ? 4 : 0;
  const f32x4 z4 = {0.f, 0.f, 0.f, 0.f};

  // ---- Phase A: gather shifted window tokens -> Xw (bf16, swizzled) ----
#pragma unroll
  for (int it = 0; it < 2; ++it) {
    int cid = tid + it * 512;                 // 1024 chunks of 8 channels
    int s = cid >> 4, cc = (cid & 15) << 3;
    int r0 = (wh * 8 + (s >> 3) + ss) & 127;  // roll(-ss): src = pos + ss (mod 128)
    int c0 = (ww * 8 + (s & 7) + ss) & 127;
    const float* src = x + ((bb * 16384 + r0 * 128 + c0) * 128 + cc);
    float4 lo = *(const float4*)src;
    float4 hi = *(const float4*)(src + 4);
    *(bf16x8*)(smem + s * 256 + ((cc * 2) ^ ((s & 7) << 4))) = packf4(lo, hi);
  }
  __syncthreads();

  // ---- Phase B: Q^T (own half) / K^T (full) / V (full) projections ----
  f32x4 qacc[2][2], kacc[2][4], vacc[4][2];
#pragma unroll
  for (int i = 0; i < 2; ++i) { qacc[i][0] = z4; qacc[i][1] = z4; }
#pragma unroll
  for (int i = 0; i < 4; ++i) {
    kacc[0][i] = z4; kacc[1][i] = z4;
    vacc[i][0] = z4; vacc[i][1] = z4;
  }
  const unsigned short* wq_ = wt + (h * 32 + c16) * 128;
  const unsigned short* wk_ = wt + 16384 + (h * 32 + c16) * 128;
  const unsigned short* wv_ = wt + 32768 + (h * 32 + c16) * 128;
#pragma unroll
  for (int kk = 0; kk < 4; ++kk) {
    const int co = kk * 32 + g * 8;
    bf16x8 xfr[4];
#pragma unroll
    for (int t = 0; t < 4; ++t) {
      int row = t * 16 + c16;
      xfr[t] = *(const bf16x8*)(smem + row * 256 + ((co * 2) ^ ((row & 7) << 4)));
    }
    bf16x8 wqf0 = *(const bf16x8*)(wq_ + co);
    bf16x8 wqf1 = *(const bf16x8*)(wq_ + 2048 + co);
    bf16x8 wkf0 = *(const bf16x8*)(wk_ + co);
    bf16x8 wkf1 = *(const bf16x8*)(wk_ + 2048 + co);
    bf16x8 wvf0 = *(const bf16x8*)(wv_ + co);
    bf16x8 wvf1 = *(const bf16x8*)(wv_ + 2048 + co);
#pragma unroll
    for (int t = 0; t < 4; ++t) {
      kacc[0][t] = MFMA16(wkf0, xfr[t], kacc[0][t]);
      kacc[1][t] = MFMA16(wkf1, xfr[t], kacc[1][t]);
      vacc[t][0] = MFMA16(xfr[t], wvf0, vacc[t][0]);
      vacc[t][1] = MFMA16(xfr[t], wvf1, vacc[t][1]);
    }
#pragma unroll
    for (int bl = 0; bl < 2; ++bl) {
      qacc[0][bl] = MFMA16(wqf0, xfr[half * 2 + bl], qacc[0][bl]);
      qacc[1][bl] = MFMA16(wqf1, xfr[half * 2 + bl], qacc[1][bl]);
    }
  }

  // bias (+ exp2-domain scale folded into Q), pack with k-mapping pi(g,j)=(j>>2)*16+g*4+(j&3)
  bf16x8 qb16[2], kb16[4], vb16[2][2];
  {
    const float scale = 0.17677669529663687f * 1.4426950408889634f;  // 1/sqrt(32)*log2e
    f32x4 bq4[2], bk4[2];
    bq4[0] = *(const f32x4*)(bq + h * 32 + g * 4);
    bq4[1] = *(const f32x4*)(bq + h * 32 + 16 + g * 4);
    bk4[0] = *(const f32x4*)(bk + h * 32 + g * 4);
    bk4[1] = *(const f32x4*)(bk + h * 32 + 16 + g * 4);
#pragma unroll
    for (int bl = 0; bl < 2; ++bl) {
      f32x4 q0, q1;
#pragma unroll
      for (int r = 0; r < 4; ++r) {
        q0[r] = (qacc[0][bl][r] + bq4[0][r]) * scale;
        q1[r] = (qacc[1][bl][r] + bq4[1][r]) * scale;
      }
      qb16[bl] = pack8(q0, q1);
    }
#pragma unroll
    for (int t = 0; t < 4; ++t) {
      f32x4 k0, k1;
#pragma unroll
      for (int r = 0; r < 4; ++r) {
        k0[r] = kacc[0][t][r] + bk4[0][r];
        k1[r] = kacc[1][t][r] + bk4[1][r];
      }
      kb16[t] = pack8(k0, k1);
    }
    float bv0 = bv[h * 32 + c16];
    float bv1 = bv[h * 32 + 16 + c16];
#pragma unroll
    for (int ks = 0; ks < 2; ++ks) {
      f32x4 v00, v10, v01, v11;
#pragma unroll
      for (int r = 0; r < 4; ++r) {
        v00[r] = vacc[2 * ks][0][r] + bv0;
        v10[r] = vacc[2 * ks + 1][0][r] + bv0;
        v01[r] = vacc[2 * ks][1][r] + bv1;
        v11[r] = vacc[2 * ks + 1][1][r] + bv1;
      }
      vb16[ks][0] = pack8(v00, v10);
      vb16[ks][1] = pack8(v01, v11);
    }
  }

  // ---- Phase C: QK^T from registers. sc[a][bl]: S^T[s2=a*16+g*4+r][s1=(half*2+bl)*16+c16]
  f32x4 sc[4][2];
#pragma unroll
  for (int a = 0; a < 4; ++a)
#pragma unroll
    for (int bl = 0; bl < 2; ++bl) sc[a][bl] = MFMA16(kb16[a], qb16[bl], z4);

  int w1i[2] = {0, 0};
  int w2i[4][4] = {};
  if (shift) {
#pragma unroll
    for (int bl = 0; bl < 2; ++bl) {
      int s1 = (half * 2 + bl) * 16 + c16;
      int r0 = (wh * 8 + (s1 >> 3) + ss) & 127;
      int c0 = (ww * 8 + (s1 & 7) + ss) & 127;
      w1i[bl] = (r0 >> 3) * 16 + (c0 >> 3);
    }
#pragma unroll
    for (int a = 0; a < 4; ++a)
#pragma unroll
      for (int r = 0; r < 4; ++r) {
        int s2 = a * 16 + g * 4 + r;
        int r0 = (wh * 8 + (s2 >> 3) + ss) & 127;
        int c0 = (ww * 8 + (s2 & 7) + ss) & 127;
        w2i[a][r] = (r0 >> 3) * 16 + (c0 >> 3);
      }
  }

  // ---- softmax over s2 (exp2 domain), tree reductions ----
  bf16x8 pa[2][2];
  const float* bfh = bias_full + h * 4096 + c16 * 64 + g * 4;
#pragma unroll
  for (int bl = 0; bl < 2; ++bl) {
    const float* bfr = bfh + (half * 2 + bl) * 1024;
    f32x4 bia[4];
#pragma unroll
    for (int a = 0; a < 4; ++a) bia[a] = *(const f32x4*)(bfr + a * 16);
#pragma unroll
    for (int a = 0; a < 4; ++a)
#pragma unroll
      for (int r = 0; r < 4; ++r) {
        float v = sc[a][bl][r] + bia[a][r];
        if (shift && (w1i[bl] != w2i[a][r])) v -= 144.2695040888963f;  // -100*log2e
        sc[a][bl][r] = v;
      }
    f32x4 m01, m23;
#pragma unroll
    for (int r = 0; r < 4; ++r) {
      m01[r] = fmaxf(sc[0][bl][r], sc[1][bl][r]);
      m23[r] = fmaxf(sc[2][bl][r], sc[3][bl][r]);
    }
    float mx = fmaxf(fmaxf(fmaxf(m01[0], m01[1]), fmaxf(m01[2], m01[3])),
                     fmaxf(fmaxf(m23[0], m23[1]), fmaxf(m23[2], m23[3])));
    mx = fmaxf(mx, __shfl_xor(mx, 16));
    mx = fmaxf(mx, __shfl_xor(mx, 32));
#pragma unroll
    for (int a = 0; a < 4; ++a)
#pragma unroll
      for (int r = 0; r < 4; ++r) sc[a][bl][r] = EXP2F(sc[a][bl][r] - mx);
    f32x4 s01, s23;
#pragma unroll
    for (int r = 0; r < 4; ++r) {
      s01[r] = sc[0][bl][r] + sc[1][bl][r];
      s23[r] = sc[2][bl][r] + sc[3][bl][r];
    }
    float sum = ((s01[0] + s01[1]) + (s01[2] + s01[3])) +
                ((s23[0] + s23[1]) + (s23[2] + s23[3]));
    sum += __shfl_xor(sum, 16);
    sum += __shfl_xor(sum, 32);
    float inv = 1.0f / sum;
#pragma unroll
    for (int a = 0; a < 4; ++a)
#pragma unroll
      for (int r = 0; r < 4; ++r) sc[a][bl][r] *= inv;
    pa[bl][0] = pack8(sc[0][bl], sc[1][bl]);
    pa[bl][1] = pack8(sc[2][bl], sc[3][bl]);
  }

  // ---- Phase D: PV. o[bl][nt]: O[s1=(half*2+bl)*16+g*4+r][d=h*32+nt*16+c16] ----
  f32x4 o[2][2];
  o[0][0] = z4; o[0][1] = z4; o[1][0] = z4; o[1][1] = z4;
#pragma unroll
  for (int bl = 0; bl < 2; ++bl)
#pragma unroll
    for (int ks = 0; ks < 2; ++ks) {
      o[bl][0] = MFMA16(pa[bl][ks], vb16[ks][0], o[bl][0]);
      o[bl][1] = MFMA16(pa[bl][ks], vb16[ks][1], o[bl][1]);
    }

  __syncthreads();  // all waves done reading Xw; reuse smem for attn-out

  // ---- Phase E: stage attn-out (bf16, swizzled rows) ----
#pragma unroll
  for (int bl = 0; bl < 2; ++bl)
#pragma unroll
    for (int nt = 0; nt < 2; ++nt)
#pragma unroll
      for (int r = 0; r < 4; ++r) {
        int row = (half * 2 + bl) * 16 + g * 4 + r;
        int col = h * 32 + nt * 16 + c16;
        *(unsigned short*)(smem + row * 256 + ((col * 2) ^ ((row & 7) << 4))) =
            f2bf1(o[bl][nt][r]);
      }
  __syncthreads();

  // ---- Phase F: output projection -> global fp32 ----
  // Wave wv: row-tile rt = wv>>1 (16 rows), col-tiles nt in [ (wv&1)*4, +4 ).
  {
    const int rt = wv >> 1, ch = wv & 1;
    f32x4 acc[4];
#pragma unroll
    for (int j = 0; j < 4; ++j) acc[j] = z4;
    const int arow = rt * 16 + c16;
    const int asw = (arow & 7) << 4;
#pragma unroll
    for (int kk = 0; kk < 4; ++kk) {
      const int co = kk * 32 + g * 8;
      bf16x8 a = *(const bf16x8*)(smem + arow * 256 + ((co * 2) ^ asw));
#pragma unroll
      for (int j = 0; j < 4; ++j) {
        bf16x8 bfr = *(const bf16x8*)(wt + 49152 + ((ch * 4 + j) * 16 + c16) * 128 + co);
        acc[j] = MFMA16(a, bfr, acc[j]);
      }
    }
#pragma unroll
    for (int j = 0; j < 4; ++j) {
      int n = (ch * 4 + j) * 16 + c16;
      float bn = bo[n];
#pragma unroll
      for (int r = 0; r < 4; ++r) {
        int row = rt * 16 + g * 4 + r;
        out[(size_t)win * 8192 + (size_t)(row * 128 + n)] = acc[j][r] + bn;
      }
    }
  }
}

extern "C" void kernel_launch(void* const* d_in, const int* in_sizes, int n_in,
                              void* d_out, int out_size, void* d_ws, size_t ws_size,
                              hipStream_t stream) {
  const float* x = (const float*)d_in[0];
  const float* wq = (const float*)d_in[1];
  const float* bq = (const float*)d_in[2];
  const float* wk = (const float*)d_in[3];
  const float* bk = (const float*)d_in[4];
  const float* wv = (const float*)d_in[5];
  const float* bv = (const float*)d_in[6];
  const float* wo = (const float*)d_in[7];
  const float* bo = (const float*)d_in[8];
  const float* bias_table = (const float*)d_in[9];
  const int* shiftp = (const int*)d_in[10];

  unsigned short* wt = (unsigned short*)d_ws;                    // 4*128*128 bf16 = 128KB
  float* bias_full = (float*)((char*)d_ws + 131072);             // 4*64*64 f32 = 64KB

  prep_kernel<<<256, 256, 0, stream>>>(wq, wk, wv, wo, bias_table, wt, bias_full);
  winattn_kernel<<<4096, 512, 0, stream>>>(x, bq, bk, bv, bo, wt, bias_full, shiftp,
                                           (float*)d_out);
}

// Round 6
// 161.693 us; speedup vs baseline: 4.0497x; 1.7929x over previous
//
#include <hip/hip_runtime.h>

// Swin shifted-window MHSA, fused per-window kernel, v5.
// 1 block = 1 window (S=64, C=128), 256 threads = 4 waves, wave h = head h.
// Register-resident attention; 3-pass QKV projection (low register peak);
// streamed score chunks (sc held 1 s1-tile at a time); shift mask baked into
// bias_full at prep (window-invariant partition); exp2-domain softmax;
// v_cvt_pk_bf16_f32 packing. 2 barriers total.

typedef __attribute__((ext_vector_type(8))) short bf16x8;   // 8 bf16 = 4 VGPR
typedef __attribute__((ext_vector_type(4))) float f32x4;    // MFMA C/D

#define MFMA16(a, b, c) __builtin_amdgcn_mfma_f32_16x16x32_bf16((a), (b), (c), 0, 0, 0)
#define EXP2F(x) __builtin_amdgcn_exp2f(x)

#define XW_OFF 0         // 16KB: Xw [64][128] bf16, row-XOR swizzled
#define STG_OFF 16384    // 16KB: attn-out staging [64][128] bf16, swizzled
#define LDS_BYTES 32768

__device__ __forceinline__ unsigned int cvt_pk(float lo, float hi) {
  unsigned int r;
  asm("v_cvt_pk_bf16_f32 %0, %1, %2" : "=v"(r) : "v"(lo), "v"(hi));
  return r;
}
__device__ __forceinline__ unsigned short f2bf1(float f) {
  return (unsigned short)(cvt_pk(f, f) & 0xffffu);
}
__device__ __forceinline__ bf16x8 pack8(f32x4 a, f32x4 b) {
  union { unsigned int w[4]; bf16x8 v; } u;
  u.w[0] = cvt_pk(a[0], a[1]); u.w[1] = cvt_pk(a[2], a[3]);
  u.w[2] = cvt_pk(b[0], b[1]); u.w[3] = cvt_pk(b[2], b[3]);
  return u.v;
}
__device__ __forceinline__ bf16x8 packf4(float4 lo, float4 hi) {
  union { unsigned int w[4]; bf16x8 v; } u;
  u.w[0] = cvt_pk(lo.x, lo.y); u.w[1] = cvt_pk(lo.z, lo.w);
  u.w[2] = cvt_pk(hi.x, hi.y); u.w[3] = cvt_pk(hi.z, hi.w);
  return u.v;
}

// prep: transpose weights to bf16 Wt[n][k] (q,k,v,o) + expand rel-pos bias to
// [4][64][64] f32 in exp2 domain, with the (window-invariant) shift mask baked in.
__global__ void prep_kernel(const float* __restrict__ wq, const float* __restrict__ wk,
                            const float* __restrict__ wv, const float* __restrict__ wo,
                            const float* __restrict__ bias_table,
                            const int* __restrict__ shiftp,
                            unsigned short* __restrict__ wt, float* __restrict__ bias_full) {
  int tid = blockIdx.x * 256 + threadIdx.x;            // 65536 threads
  int m = tid >> 14, idx = tid & 16383;
  int n = idx >> 7, k = idx & 127;
  const float* w = (m == 0) ? wq : (m == 1) ? wk : (m == 2) ? wv : wo;
  wt[m * 16384 + n * 128 + k] = f2bf1(w[k * 128 + n]);
  if (tid < 16384) {                                    // bias_full[h][s1][s2]
    int h = tid >> 12, r = tid & 4095;
    int s1 = r >> 6, s2 = r & 63;
    int rel = ((s1 >> 3) - (s2 >> 3) + 7) * 15 + ((s1 & 7) - (s2 & 7) + 7);
    float v = bias_table[rel * 4 + h];
    // shifted-window mask: partition by (row>=4, col>=4) within the window --
    // identical for every window when H,W are multiples of WS and roll wraps.
    if (shiftp[0]) {
      int same = (((s1 >> 3) >= 4) == ((s2 >> 3) >= 4)) &
                 (((s1 & 7) >= 4) == ((s2 & 7) >= 4));
      if (!same) v -= 100.0f;
    }
    bias_full[tid] = v * 1.4426950408889634f;           // * log2(e)
  }
}

__global__ __launch_bounds__(256) void winattn_kernel(
    const float* __restrict__ x,
    const float* __restrict__ bq, const float* __restrict__ bk,
    const float* __restrict__ bv, const float* __restrict__ bo,
    const unsigned short* __restrict__ wt,
    const float* __restrict__ bias_full,
    const int* __restrict__ shiftp,
    float* __restrict__ out) {
  __shared__ __align__(16) char smem[LDS_BYTES];
  const int tid = threadIdx.x;
  const int h = tid >> 6, lane = tid & 63;
  const int g = lane >> 4, c16 = lane & 15;
  const int win = blockIdx.x;
  const int bb = win >> 8, wh = (win >> 4) & 15, ww = win & 15;
  const int ss = shiftp[0] ? 4 : 0;
  const f32x4 z4 = {0.f, 0.f, 0.f, 0.f};

  // ---- Phase A: gather shifted window tokens -> Xw (bf16, swizzled) ----
#pragma unroll
  for (int it = 0; it < 4; ++it) {
    int cid = tid + it * 256;                 // 1024 chunks of 8 channels
    int s = cid >> 4, cc = (cid & 15) << 3;
    int r0 = (wh * 8 + (s >> 3) + ss) & 127;  // roll(-ss): src = pos + ss (mod 128)
    int c0 = (ww * 8 + (s & 7) + ss) & 127;
    const float* src = x + ((bb * 16384 + r0 * 128 + c0) * 128 + cc);
    float4 lo = *(const float4*)src;
    float4 hi = *(const float4*)(src + 4);
    *(bf16x8*)(smem + XW_OFF + s * 256 + ((cc * 2) ^ ((s & 7) << 4))) = packf4(lo, hi);
  }
  __syncthreads();

  // ---- Phase B: three passes (K, V, Q) to keep register peak low ----
  bf16x8 qb16[4], kb16[4], vb16[2][2];
  const unsigned short* wq_ = wt + (h * 32 + c16) * 128;
  const unsigned short* wk_ = wt + 16384 + (h * 32 + c16) * 128;
  const unsigned short* wv_ = wt + 32768 + (h * 32 + c16) * 128;

  {  // pass K: K^T[ch][s2] = Wk rows x Xw^T
    f32x4 a0[4], a1[4];
#pragma unroll
    for (int t = 0; t < 4; ++t) { a0[t] = z4; a1[t] = z4; }
#pragma unroll
    for (int kk = 0; kk < 4; ++kk) {
      const int co = kk * 32 + g * 8;
      bf16x8 wf0 = *(const bf16x8*)(wk_ + co);
      bf16x8 wf1 = *(const bf16x8*)(wk_ + 2048 + co);
#pragma unroll
      for (int t = 0; t < 4; ++t) {
        int row = t * 16 + c16;
        bf16x8 xf = *(const bf16x8*)(smem + XW_OFF + row * 256 + ((co * 2) ^ ((row & 7) << 4)));
        a0[t] = MFMA16(wf0, xf, a0[t]);
        a1[t] = MFMA16(wf1, xf, a1[t]);
      }
    }
    f32x4 b0 = *(const f32x4*)(bk + h * 32 + g * 4);
    f32x4 b1 = *(const f32x4*)(bk + h * 32 + 16 + g * 4);
#pragma unroll
    for (int t = 0; t < 4; ++t) {
      f32x4 k0, k1;
#pragma unroll
      for (int r = 0; r < 4; ++r) { k0[r] = a0[t][r] + b0[r]; k1[r] = a1[t][r] + b1[r]; }
      kb16[t] = pack8(k0, k1);
    }
  }

  {  // pass V: V[s2][d] = Xw x Wv
    f32x4 a0[4], a1[4];
#pragma unroll
    for (int t = 0; t < 4; ++t) { a0[t] = z4; a1[t] = z4; }
#pragma unroll
    for (int kk = 0; kk < 4; ++kk) {
      const int co = kk * 32 + g * 8;
      bf16x8 wf0 = *(const bf16x8*)(wv_ + co);
      bf16x8 wf1 = *(const bf16x8*)(wv_ + 2048 + co);
#pragma unroll
      for (int t = 0; t < 4; ++t) {
        int row = t * 16 + c16;
        bf16x8 xf = *(const bf16x8*)(smem + XW_OFF + row * 256 + ((co * 2) ^ ((row & 7) << 4)));
        a0[t] = MFMA16(xf, wf0, a0[t]);
        a1[t] = MFMA16(xf, wf1, a1[t]);
      }
    }
    float bv0 = bv[h * 32 + c16];
    float bv1 = bv[h * 32 + 16 + c16];
#pragma unroll
    for (int ks = 0; ks < 2; ++ks) {
      f32x4 v00, v10, v01, v11;
#pragma unroll
      for (int r = 0; r < 4; ++r) {
        v00[r] = a0[2 * ks][r] + bv0;
        v10[r] = a0[2 * ks + 1][r] + bv0;
        v01[r] = a1[2 * ks][r] + bv1;
        v11[r] = a1[2 * ks + 1][r] + bv1;
      }
      vb16[ks][0] = pack8(v00, v10);
      vb16[ks][1] = pack8(v01, v11);
    }
  }

  {  // pass Q: Q^T[ch][s1], scale*log2e folded
    f32x4 a0[4], a1[4];
#pragma unroll
    for (int t = 0; t < 4; ++t) { a0[t] = z4; a1[t] = z4; }
#pragma unroll
    for (int kk = 0; kk < 4; ++kk) {
      const int co = kk * 32 + g * 8;
      bf16x8 wf0 = *(const bf16x8*)(wq_ + co);
      bf16x8 wf1 = *(const bf16x8*)(wq_ + 2048 + co);
#pragma unroll
      for (int t = 0; t < 4; ++t) {
        int row = t * 16 + c16;
        bf16x8 xf = *(const bf16x8*)(smem + XW_OFF + row * 256 + ((co * 2) ^ ((row & 7) << 4)));
        a0[t] = MFMA16(wf0, xf, a0[t]);
        a1[t] = MFMA16(wf1, xf, a1[t]);
      }
    }
    const float scale = 0.17677669529663687f * 1.4426950408889634f;  // 1/sqrt(32)*log2e
    f32x4 b0 = *(const f32x4*)(bq + h * 32 + g * 4);
    f32x4 b1 = *(const f32x4*)(bq + h * 32 + 16 + g * 4);
#pragma unroll
    for (int t = 0; t < 4; ++t) {
      f32x4 q0, q1;
#pragma unroll
      for (int r = 0; r < 4; ++r) {
        q0[r] = (a0[t][r] + b0[r]) * scale;
        q1[r] = (a1[t][r] + b1[r]) * scale;
      }
      qb16[t] = pack8(q0, q1);
    }
  }

  // ---- Phases C/D streamed per s1-chunk: QK -> softmax -> PV -> stage ----
  const float* bfh = bias_full + h * 4096 + c16 * 64 + g * 4;
#pragma unroll
  for (int b = 0; b < 4; ++b) {
    f32x4 s0 = MFMA16(kb16[0], qb16[b], z4);
    f32x4 s1 = MFMA16(kb16[1], qb16[b], z4);
    f32x4 s2 = MFMA16(kb16[2], qb16[b], z4);
    f32x4 s3 = MFMA16(kb16[3], qb16[b], z4);
    const float* bfr = bfh + b * 1024;
    f32x4 bia0 = *(const f32x4*)(bfr);
    f32x4 bia1 = *(const f32x4*)(bfr + 16);
    f32x4 bia2 = *(const f32x4*)(bfr + 32);
    f32x4 bia3 = *(const f32x4*)(bfr + 48);
#pragma unroll
    for (int r = 0; r < 4; ++r) {
      s0[r] += bia0[r]; s1[r] += bia1[r]; s2[r] += bia2[r]; s3[r] += bia3[r];
    }
    f32x4 m01, m23;
#pragma unroll
    for (int r = 0; r < 4; ++r) {
      m01[r] = fmaxf(s0[r], s1[r]);
      m23[r] = fmaxf(s2[r], s3[r]);
    }
    float mx = fmaxf(fmaxf(fmaxf(m01[0], m01[1]), fmaxf(m01[2], m01[3])),
                     fmaxf(fmaxf(m23[0], m23[1]), fmaxf(m23[2], m23[3])));
    mx = fmaxf(mx, __shfl_xor(mx, 16));
    mx = fmaxf(mx, __shfl_xor(mx, 32));
#pragma unroll
    for (int r = 0; r < 4; ++r) {
      s0[r] = EXP2F(s0[r] - mx); s1[r] = EXP2F(s1[r] - mx);
      s2[r] = EXP2F(s2[r] - mx); s3[r] = EXP2F(s3[r] - mx);
    }
    f32x4 t01, t23;
#pragma unroll
    for (int r = 0; r < 4; ++r) {
      t01[r] = s0[r] + s1[r];
      t23[r] = s2[r] + s3[r];
    }
    float sum = ((t01[0] + t01[1]) + (t01[2] + t01[3])) +
                ((t23[0] + t23[1]) + (t23[2] + t23[3]));
    sum += __shfl_xor(sum, 16);
    sum += __shfl_xor(sum, 32);
    float inv = 1.0f / sum;
#pragma unroll
    for (int r = 0; r < 4; ++r) {
      s0[r] *= inv; s1[r] *= inv; s2[r] *= inv; s3[r] *= inv;
    }
    bf16x8 pa0 = pack8(s0, s1);
    bf16x8 pa1 = pack8(s2, s3);

    f32x4 o0 = MFMA16(pa0, vb16[0][0], z4);
    f32x4 o1 = MFMA16(pa0, vb16[0][1], z4);
    o0 = MFMA16(pa1, vb16[1][0], o0);
    o1 = MFMA16(pa1, vb16[1][1], o1);

    // stage attn-out rows for this chunk (own region; barrier after loop)
#pragma unroll
    for (int r = 0; r < 4; ++r) {
      int row = b * 16 + g * 4 + r;
      int sw = (row & 7) << 4;
      int col0 = h * 32 + c16;
      *(unsigned short*)(smem + STG_OFF + row * 256 + ((col0 * 2) ^ sw)) = f2bf1(o0[r]);
      *(unsigned short*)(smem + STG_OFF + row * 256 + (((col0 + 16) * 2) ^ sw)) = f2bf1(o1[r]);
    }
  }
  __syncthreads();   // STG complete across waves

  // ---- Phase F: output projection -> global fp32 ----
  {
    f32x4 acc[8];
#pragma unroll
    for (int nt = 0; nt < 8; ++nt) acc[nt] = z4;
    const int arow = h * 16 + c16;
    const int asw = (arow & 7) << 4;
#pragma unroll
    for (int kk = 0; kk < 4; ++kk) {
      const int co = kk * 32 + g * 8;
      bf16x8 a = *(const bf16x8*)(smem + STG_OFF + arow * 256 + ((co * 2) ^ asw));
#pragma unroll
      for (int nt = 0; nt < 8; ++nt) {
        bf16x8 bfr = *(const bf16x8*)(wt + 49152 + (nt * 16 + c16) * 128 + co);
        acc[nt] = MFMA16(a, bfr, acc[nt]);
      }
    }
#pragma unroll
    for (int nt = 0; nt < 8; ++nt) {
      int n = nt * 16 + c16;
      float bn = bo[n];
#pragma unroll
      for (int r = 0; r < 4; ++r) {
        int row = h * 16 + g * 4 + r;
        out[(size_t)win * 8192 + (size_t)(row * 128 + n)] = acc[nt][r] + bn;
      }
    }
  }
}

extern "C" void kernel_launch(void* const* d_in, const int* in_sizes, int n_in,
                              void* d_out, int out_size, void* d_ws, size_t ws_size,
                              hipStream_t stream) {
  const float* x = (const float*)d_in[0];
  const float* wq = (const float*)d_in[1];
  const float* bq = (const float*)d_in[2];
  const float* wk = (const float*)d_in[3];
  const float* bk = (const float*)d_in[4];
  const float* wv = (const float*)d_in[5];
  const float* bv = (const float*)d_in[6];
  const float* wo = (const float*)d_in[7];
  const float* bo = (const float*)d_in[8];
  const float* bias_table = (const float*)d_in[9];
  const int* shiftp = (const int*)d_in[10];

  unsigned short* wt = (unsigned short*)d_ws;                    // 4*128*128 bf16 = 128KB
  float* bias_full = (float*)((char*)d_ws + 131072);             // 4*64*64 f32 = 64KB

  prep_kernel<<<256, 256, 0, stream>>>(wq, wk, wv, wo, bias_table, shiftp, wt, bias_full);
  winattn_kernel<<<4096, 256, 0, stream>>>(x, bq, bk, bv, bo, wt, bias_full, shiftp,
                                           (float*)d_out);
}